// Round 1
// baseline (1302.175 us; speedup 1.0000x reference)
//
#include <hip/hip_runtime.h>
#include <hip/hip_bf16.h>

// Problem constants (fixed by setup_inputs)
#define BATCH 2
#define NN 32768
#define DIM 512
#define HEADS 8
#define DHEAD 64
#define INNER 512
#define G 32
#define M_ROWS (BATCH * NN)   // 65536

typedef __attribute__((ext_vector_type(8))) short bf16x8;
typedef __attribute__((ext_vector_type(4))) float floatx4;

// ---------------------------------------------------------------------------
// Kernel 1: graph sizes / starts / inverse sizes from sorted batch array
// ---------------------------------------------------------------------------
__global__ void graph_info_kernel(const int* __restrict__ batch,
                                  int* __restrict__ starts,
                                  int* __restrict__ sizes,
                                  float* __restrict__ inv) {
    __shared__ int cnt[G];
    int t = threadIdx.x;
    if (t < G) cnt[t] = 0;
    __syncthreads();
    for (int n = t; n < NN; n += blockDim.x) atomicAdd(&cnt[batch[n]], 1);
    __syncthreads();
    if (t == 0) {
        int acc = 0;
        for (int g = 0; g < G; g++) { starts[g] = acc; int c = cnt[g]; sizes[g] = c; acc += c; }
    }
    if (t < G) inv[t] = cnt[t] ? 1.0f / (float)cnt[t] : 0.0f;
}

// ---------------------------------------------------------------------------
// Kernel 2: QKV GEMM.  Y = x(65536x512) @ w_qkv(1536x512)^T, bf16 MFMA.
// 64x64 tile per block (256 thr = 4 waves; wave w handles rows [16w,16w+16)).
// Output written as bf16 into q/k/v buffers laid out [B][H][N][64]
// (each 64-wide column tile is exactly one (sel,head)).
// ---------------------------------------------------------------------------
__global__ __launch_bounds__(256) void qkv_gemm_kernel(
        const float* __restrict__ x, const float* __restrict__ w,
        __hip_bfloat16* __restrict__ qb, __hip_bfloat16* __restrict__ kb,
        __hip_bfloat16* __restrict__ vb) {
    __shared__ __hip_bfloat16 As[64][40];   // padded: 80B rows -> 2-way conflicts only
    __shared__ __hip_bfloat16 Bs[64][40];
    const int row0 = blockIdx.x * 64;
    const int col0 = blockIdx.y * 64;       // in [0,1536)
    const int t = threadIdx.x;
    const int lane = t & 63;
    const int wave = t >> 6;
    const int quad = lane >> 4;
    const int lr = lane & 15;

    floatx4 acc[4] = {floatx4{0,0,0,0}, floatx4{0,0,0,0}, floatx4{0,0,0,0}, floatx4{0,0,0,0}};

    const int r = t >> 2;          // 0..63
    const int cs = (t & 3) * 8;    // 0,8,16,24

    for (int k0 = 0; k0 < DIM; k0 += 32) {
        // stage A (x) and B (w_qkv) tiles, fp32 -> bf16
        {
            const float* srcA = x + (size_t)(row0 + r) * DIM + k0 + cs;
            float4 a0 = ((const float4*)srcA)[0];
            float4 a1 = ((const float4*)srcA)[1];
            As[r][cs + 0] = __float2bfloat16(a0.x); As[r][cs + 1] = __float2bfloat16(a0.y);
            As[r][cs + 2] = __float2bfloat16(a0.z); As[r][cs + 3] = __float2bfloat16(a0.w);
            As[r][cs + 4] = __float2bfloat16(a1.x); As[r][cs + 5] = __float2bfloat16(a1.y);
            As[r][cs + 6] = __float2bfloat16(a1.z); As[r][cs + 7] = __float2bfloat16(a1.w);
            const float* srcB = w + (size_t)(col0 + r) * DIM + k0 + cs;
            float4 b0 = ((const float4*)srcB)[0];
            float4 b1 = ((const float4*)srcB)[1];
            Bs[r][cs + 0] = __float2bfloat16(b0.x); Bs[r][cs + 1] = __float2bfloat16(b0.y);
            Bs[r][cs + 2] = __float2bfloat16(b0.z); Bs[r][cs + 3] = __float2bfloat16(b0.w);
            Bs[r][cs + 4] = __float2bfloat16(b1.x); Bs[r][cs + 5] = __float2bfloat16(b1.y);
            Bs[r][cs + 6] = __float2bfloat16(b1.z); Bs[r][cs + 7] = __float2bfloat16(b1.w);
        }
        __syncthreads();
        // A frag: A[m = wave*16+lr][k = quad*8 + j]
        bf16x8 afr = *reinterpret_cast<const bf16x8*>(&As[wave * 16 + lr][quad * 8]);
        #pragma unroll
        for (int jt = 0; jt < 4; jt++) {
            bf16x8 bfr = *reinterpret_cast<const bf16x8*>(&Bs[jt * 16 + lr][quad * 8]);
            acc[jt] = __builtin_amdgcn_mfma_f32_16x16x32_bf16(afr, bfr, acc[jt], 0, 0, 0);
        }
        __syncthreads();
    }

    // epilogue: C[row][col], row=(lane>>4)*4+reg, col=lane&15 (per 16x16 tile)
    const int sel = col0 >> 9;               // 0=q 1=k 2=v
    const int hh = (col0 & 511) >> 6;        // head
    __hip_bfloat16* dst = sel == 0 ? qb : (sel == 1 ? kb : vb);
    #pragma unroll
    for (int jt = 0; jt < 4; jt++) {
        #pragma unroll
        for (int reg = 0; reg < 4; reg++) {
            int row = row0 + wave * 16 + quad * 4 + reg;
            int d = jt * 16 + lr;
            int b = row >> 15;
            int n = row & (NN - 1);
            dst[(((size_t)(b * HEADS + hh) << 15) + n) * 64 + d] = __float2bfloat16(acc[jt][reg]);
        }
    }
}

// ---------------------------------------------------------------------------
// Kernel 3: per-row LayerNorm on k and v; scale q by 1/size. One wave per row.
// ---------------------------------------------------------------------------
__global__ __launch_bounds__(256) void ln_kernel(
        __hip_bfloat16* __restrict__ q, __hip_bfloat16* __restrict__ k,
        __hip_bfloat16* __restrict__ v,
        const float* __restrict__ ln1w, const float* __restrict__ ln1b,
        const float* __restrict__ ln2w, const float* __restrict__ ln2b,
        const float* __restrict__ inv, const int* __restrict__ batch) {
    int gid = blockIdx.x * 4 + (threadIdx.x >> 6);   // row over [B*H*N)
    int lane = threadIdx.x & 63;
    int n = gid & (NN - 1);
    size_t base = (size_t)gid * 64 + lane;

    // q scaling
    float qv = __bfloat162float(q[base]) * inv[batch[n]];
    q[base] = __float2bfloat16(qv);

    // k layernorm
    {
        float kv = __bfloat162float(k[base]);
        float s = kv;
        for (int off = 32; off >= 1; off >>= 1) s += __shfl_xor(s, off);
        float mu = s * (1.0f / 64.0f);
        float dd = kv - mu;
        float s2 = dd * dd;
        for (int off = 32; off >= 1; off >>= 1) s2 += __shfl_xor(s2, off);
        float rstd = rsqrtf(s2 * (1.0f / 64.0f) + 1e-6f);
        k[base] = __float2bfloat16(dd * rstd * ln1w[lane] + ln1b[lane]);
    }
    // v layernorm
    {
        float vv = __bfloat162float(v[base]);
        float s = vv;
        for (int off = 32; off >= 1; off >>= 1) s += __shfl_xor(s, off);
        float mu = s * (1.0f / 64.0f);
        float dd = vv - mu;
        float s2 = dd * dd;
        for (int off = 32; off >= 1; off >>= 1) s2 += __shfl_xor(s2, off);
        float rstd = rsqrtf(s2 * (1.0f / 64.0f) + 1e-6f);
        v[base] = __float2bfloat16(dd * rstd * ln2w[lane] + ln2b[lane]);
    }
}

// ---------------------------------------------------------------------------
// Kernel 4: ktv[b,h,g] = sum_{n in g} k[n] (outer) v[n]  (64x64 fp32)
// One block per (b,h,g) = 512 blocks. Thread owns a 4x4 sub-block.
// ---------------------------------------------------------------------------
__global__ __launch_bounds__(256) void ktv_kernel(
        const __hip_bfloat16* __restrict__ k, const __hip_bfloat16* __restrict__ v,
        const int* __restrict__ starts, const int* __restrict__ sizes,
        float* __restrict__ ktv) {
    __shared__ float ksh[4][64];
    __shared__ float vsh[4][64];
    const int bhg = blockIdx.x;          // [0,512)
    const int g = bhg & 31;
    const int bh = bhg >> 5;             // [0,16)
    const int s0 = starts[g];
    const int sz = sizes[g];
    const int t = threadIdx.x;
    const int dbase = (t >> 4) * 4;
    const int ebase = (t & 15) * 4;

    float acc[4][4] = {};

    for (int i = 0; i < sz; i += 4) {
        __syncthreads();
        #pragma unroll
        for (int u = 0; u < 2; u++) {
            int idx = t * 2 + u;              // 0..511
            int which = idx >> 8;             // 0=k 1=v
            int rowi = (idx >> 6) & 3;
            int d = idx & 63;
            int node = i + rowi;
            float val = 0.f;
            if (node < sz) {
                const __hip_bfloat16* src = which ? v : k;
                val = __bfloat162float(src[((size_t)bh * NN + s0 + node) * 64 + d]);
            }
            if (which) vsh[rowi][d] = val; else ksh[rowi][d] = val;
        }
        __syncthreads();
        #pragma unroll
        for (int rr = 0; rr < 4; rr++) {
            float4 kk = *reinterpret_cast<const float4*>(&ksh[rr][dbase]);
            float4 vv = *reinterpret_cast<const float4*>(&vsh[rr][ebase]);
            acc[0][0] += kk.x * vv.x; acc[0][1] += kk.x * vv.y; acc[0][2] += kk.x * vv.z; acc[0][3] += kk.x * vv.w;
            acc[1][0] += kk.y * vv.x; acc[1][1] += kk.y * vv.y; acc[1][2] += kk.y * vv.z; acc[1][3] += kk.y * vv.w;
            acc[2][0] += kk.z * vv.x; acc[2][1] += kk.z * vv.y; acc[2][2] += kk.z * vv.z; acc[2][3] += kk.z * vv.w;
            acc[3][0] += kk.w * vv.x; acc[3][1] += kk.w * vv.y; acc[3][2] += kk.w * vv.z; acc[3][3] += kk.w * vv.w;
        }
    }
    float* out = ktv + (size_t)bhg * 4096;
    #pragma unroll
    for (int di = 0; di < 4; di++)
        #pragma unroll
        for (int ei = 0; ei < 4; ei++)
            out[(dbase + di) * 64 + ebase + ei] = acc[di][ei];
}

// ---------------------------------------------------------------------------
// Kernel 5: og[b,n,h*64+e] = sum_d qn[b,h,n,d] * ktv[b,h,g(n),d,e]   (bf16 out)
// Grid (512 bhg, 8 chunks). ktv tile in LDS; 8 nodes per pass.
// ---------------------------------------------------------------------------
__global__ __launch_bounds__(256) void apply_kernel(
        const __hip_bfloat16* __restrict__ q, const float* __restrict__ ktv,
        const int* __restrict__ starts, const int* __restrict__ sizes,
        __hip_bfloat16* __restrict__ og) {
    __shared__ float kt_sh[64][64];   // 16 KB
    __shared__ float q_sh[8][64];
    const int bhg = blockIdx.x;
    const int chunk = blockIdx.y;     // [0,8)
    const int g = bhg & 31;
    const int bh = bhg >> 5;
    const int b = bh >> 3;
    const int h = bh & 7;
    const int s0 = starts[g];
    const int sz = sizes[g];
    const int t = threadIdx.x;

    {
        const float4* src = reinterpret_cast<const float4*>(ktv + (size_t)bhg * 4096);
        float4* dst = reinterpret_cast<float4*>(&kt_sh[0][0]);
        #pragma unroll
        for (int i = 0; i < 4; i++) dst[t + 256 * i] = src[t + 256 * i];
    }

    const int len = (sz + 7) >> 3;
    const int n0 = chunk * len;
    const int n1 = min(n0 + len, sz);
    const int e2 = (t & 31) * 2;
    const int ns = t >> 5;

    for (int base = n0; base < n1; base += 8) {
        __syncthreads();
        #pragma unroll
        for (int u = 0; u < 2; u++) {
            int idx = t * 2 + u;
            int rr = idx >> 6;
            int d = idx & 63;
            int node = base + rr;
            q_sh[rr][d] = (node < n1)
                ? __bfloat162float(q[((size_t)bh * NN + s0 + node) * 64 + d]) : 0.f;
        }
        __syncthreads();
        float a0 = 0.f, a1 = 0.f;
        #pragma unroll 8
        for (int d = 0; d < 64; d++) {
            float qd = q_sh[ns][d];
            float2 kt = *reinterpret_cast<const float2*>(&kt_sh[d][e2]);
            a0 += qd * kt.x;
            a1 += qd * kt.y;
        }
        int node = base + ns;
        if (node < n1) {
            size_t o = ((size_t)b * NN + s0 + node) * INNER + h * 64 + e2;
            og[o]     = __float2bfloat16(a0);
            og[o + 1] = __float2bfloat16(a1);
        }
    }
}

// ---------------------------------------------------------------------------
// Kernel 6: out = og(65536x512,bf16) @ w_out(512x512)^T + b_out  -> fp32 d_out
// ---------------------------------------------------------------------------
__global__ __launch_bounds__(256) void out_gemm_kernel(
        const __hip_bfloat16* __restrict__ og, const float* __restrict__ w,
        const float* __restrict__ bias, float* __restrict__ out) {
    __shared__ __hip_bfloat16 As[64][40];
    __shared__ __hip_bfloat16 Bs[64][40];
    const int row0 = blockIdx.x * 64;
    const int col0 = blockIdx.y * 64;
    const int t = threadIdx.x;
    const int lane = t & 63;
    const int wave = t >> 6;
    const int quad = lane >> 4;
    const int lr = lane & 15;

    floatx4 acc[4] = {floatx4{0,0,0,0}, floatx4{0,0,0,0}, floatx4{0,0,0,0}, floatx4{0,0,0,0}};

    const int r = t >> 2;
    const int cs = (t & 3) * 8;

    for (int k0 = 0; k0 < INNER; k0 += 32) {
        // A: raw 16B bf16 copy
        *reinterpret_cast<float4*>(&As[r][cs]) =
            *reinterpret_cast<const float4*>(og + (size_t)(row0 + r) * INNER + k0 + cs);
        // B: fp32 -> bf16
        {
            const float* srcB = w + (size_t)(col0 + r) * INNER + k0 + cs;
            float4 b0 = ((const float4*)srcB)[0];
            float4 b1 = ((const float4*)srcB)[1];
            Bs[r][cs + 0] = __float2bfloat16(b0.x); Bs[r][cs + 1] = __float2bfloat16(b0.y);
            Bs[r][cs + 2] = __float2bfloat16(b0.z); Bs[r][cs + 3] = __float2bfloat16(b0.w);
            Bs[r][cs + 4] = __float2bfloat16(b1.x); Bs[r][cs + 5] = __float2bfloat16(b1.y);
            Bs[r][cs + 6] = __float2bfloat16(b1.z); Bs[r][cs + 7] = __float2bfloat16(b1.w);
        }
        __syncthreads();
        bf16x8 afr = *reinterpret_cast<const bf16x8*>(&As[wave * 16 + lr][quad * 8]);
        #pragma unroll
        for (int jt = 0; jt < 4; jt++) {
            bf16x8 bfr = *reinterpret_cast<const bf16x8*>(&Bs[jt * 16 + lr][quad * 8]);
            acc[jt] = __builtin_amdgcn_mfma_f32_16x16x32_bf16(afr, bfr, acc[jt], 0, 0, 0);
        }
        __syncthreads();
    }

    #pragma unroll
    for (int jt = 0; jt < 4; jt++) {
        int col = col0 + jt * 16 + lr;
        float bv = bias[col];
        #pragma unroll
        for (int reg = 0; reg < 4; reg++) {
            int row = row0 + wave * 16 + quad * 4 + reg;
            out[(size_t)row * DIM + col] = acc[jt][reg] + bv;
        }
    }
}

// ---------------------------------------------------------------------------
extern "C" void kernel_launch(void* const* d_in, const int* in_sizes, int n_in,
                              void* d_out, int out_size, void* d_ws, size_t ws_size,
                              hipStream_t stream) {
    const float* x     = (const float*)d_in[0];
    const float* w_qkv = (const float*)d_in[1];
    const float* ln1w  = (const float*)d_in[2];
    const float* ln1b  = (const float*)d_in[3];
    const float* ln2w  = (const float*)d_in[4];
    const float* ln2b  = (const float*)d_in[5];
    const float* w_out = (const float*)d_in[6];
    const float* b_out = (const float*)d_in[7];
    const int*   batch = (const int*)d_in[8];
    float* out = (float*)d_out;

    char* ws = (char*)d_ws;
    const size_t MB = 1u << 20;
    __hip_bfloat16* qb  = (__hip_bfloat16*)(ws);              // 64 MB
    __hip_bfloat16* kb  = (__hip_bfloat16*)(ws + 64 * MB);    // 64 MB
    __hip_bfloat16* vb  = (__hip_bfloat16*)(ws + 128 * MB);   // 64 MB
    float*          ktv = (float*)(ws + 192 * MB);            // 8 MB
    __hip_bfloat16* og  = (__hip_bfloat16*)(ws + 200 * MB);   // 64 MB
    int*   starts = (int*)(ws + 264 * MB);
    int*   sizes  = (int*)(ws + 264 * MB + 4096);
    float* inv    = (float*)(ws + 264 * MB + 8192);

    graph_info_kernel<<<1, 256, 0, stream>>>(batch, starts, sizes, inv);
    qkv_gemm_kernel<<<dim3(M_ROWS / 64, (3 * INNER) / 64), 256, 0, stream>>>(
        x, w_qkv, qb, kb, vb);
    ln_kernel<<<(BATCH * HEADS * NN) / 4, 256, 0, stream>>>(
        qb, kb, vb, ln1w, ln1b, ln2w, ln2b, inv, batch);
    ktv_kernel<<<BATCH * HEADS * G, 256, 0, stream>>>(kb, vb, starts, sizes, ktv);
    apply_kernel<<<dim3(BATCH * HEADS * G, 8), 256, 0, stream>>>(
        qb, ktv, starts, sizes, og);
    out_gemm_kernel<<<dim3(M_ROWS / 64, DIM / 64), 256, 0, stream>>>(
        og, w_out, b_out, out);
}

// Round 2
// 869.281 us; speedup vs baseline: 1.4980x; 1.4980x over previous
//
#include <hip/hip_runtime.h>
#include <hip/hip_bf16.h>
#include <stdint.h>

// Problem constants (fixed by setup_inputs)
#define BATCH 2
#define NN 32768
#define DIM 512
#define HEADS 8
#define INNER 512
#define G 32
#define M_ROWS (BATCH * NN)   // 65536

typedef __attribute__((ext_vector_type(8))) short bf16x8;
typedef __attribute__((ext_vector_type(4))) float floatx4;

// async global->LDS 16B copy. LDS dest is wave-uniform base + lane*16; we pass
// per-thread base + t*16 whose first-lane value is the wave base (m97 pattern).
__device__ __forceinline__ void gl_lds16(const void* g, void* l) {
    __builtin_amdgcn_global_load_lds(
        (const __attribute__((address_space(1))) uint32_t*)g,
        (__attribute__((address_space(3))) uint32_t*)l, 16, 0, 0);
}

// ---------------------------------------------------------------------------
// graph info via binary search over sorted batch
// ---------------------------------------------------------------------------
__global__ void graph_info_kernel(const int* __restrict__ batch,
                                  int* __restrict__ starts,
                                  int* __restrict__ sizes,
                                  float* __restrict__ inv) {
    __shared__ int bound[G + 1];
    int g = threadIdx.x;
    if (g <= G) {
        int lo = 0, hi = NN;
        while (lo < hi) { int mid = (lo + hi) >> 1; if (batch[mid] < g) lo = mid + 1; else hi = mid; }
        bound[g] = lo;
    }
    __syncthreads();
    if (g < G) {
        int s0 = bound[g], s1 = bound[g + 1];
        starts[g] = s0;
        int c = s1 - s0;
        sizes[g] = c;
        inv[g] = c ? 1.0f / (float)c : 0.0f;
    }
}

// ---------------------------------------------------------------------------
// fp32 -> bf16 convert, 8 elements/thread
// ---------------------------------------------------------------------------
__global__ __launch_bounds__(256) void convert_kernel(
        const float* __restrict__ in, __hip_bfloat16* __restrict__ out, int n8) {
    int i = blockIdx.x * 256 + threadIdx.x;
    if (i >= n8) return;
    const float4* p = reinterpret_cast<const float4*>(in) + (size_t)i * 2;
    float4 a = p[0], b = p[1];
    __hip_bfloat16 o[8];
    o[0] = __float2bfloat16(a.x); o[1] = __float2bfloat16(a.y);
    o[2] = __float2bfloat16(a.z); o[3] = __float2bfloat16(a.w);
    o[4] = __float2bfloat16(b.x); o[5] = __float2bfloat16(b.y);
    o[6] = __float2bfloat16(b.z); o[7] = __float2bfloat16(b.w);
    *reinterpret_cast<float4*>(out + (size_t)i * 8) = *reinterpret_cast<float4*>(o);
}

// ---------------------------------------------------------------------------
// QKV GEMM, 128x128 tile, global_load_lds staging, bf16 MFMA.
// Fused epilogue: q scaled by 1/size; k,v layernormed per head-row.
// Grid (512, 12); 256 threads = 4 waves in 2x2; wave computes 64x64.
// ---------------------------------------------------------------------------
__global__ __launch_bounds__(256) void qkv_gemm_kernel(
        const __hip_bfloat16* __restrict__ xb, const __hip_bfloat16* __restrict__ wb,
        const float* __restrict__ ln1w, const float* __restrict__ ln1b,
        const float* __restrict__ ln2w, const float* __restrict__ ln2b,
        const float* __restrict__ inv, const int* __restrict__ batch,
        __hip_bfloat16* __restrict__ qb, __hip_bfloat16* __restrict__ kb,
        __hip_bfloat16* __restrict__ vb) {
    __shared__ __hip_bfloat16 As[128][32];   // 8 KB, unpadded (global_load_lds layout)
    __shared__ __hip_bfloat16 Bs[128][32];   // 8 KB
    const int row0 = blockIdx.x * 128;
    const int col0 = blockIdx.y * 128;
    const int t = threadIdx.x;
    const int lane = t & 63;
    const int wave = t >> 6;
    const int wr = wave >> 1, wc = wave & 1;
    const int quad = lane >> 4, lr = lane & 15;

    floatx4 acc[4][4] = {};

    const int srow = t >> 2;          // 0..63
    const int scol = (t & 3) * 8;     // bf16 elems
    const __hip_bfloat16* gA = xb + (size_t)(row0 + srow) * DIM + scol;
    const __hip_bfloat16* gB = wb + (size_t)(col0 + srow) * DIM + scol;
    char* lA = (char*)&As[0][0] + t * 16;
    char* lB = (char*)&Bs[0][0] + t * 16;

    for (int k0 = 0; k0 < DIM; k0 += 32) {
        gl_lds16(gA + k0, lA);
        gl_lds16(gA + (size_t)64 * DIM + k0, lA + 4096);
        gl_lds16(gB + k0, lB);
        gl_lds16(gB + (size_t)64 * DIM + k0, lB + 4096);
        __syncthreads();
        bf16x8 af[4], bf[4];
        #pragma unroll
        for (int mt = 0; mt < 4; mt++)
            af[mt] = *reinterpret_cast<const bf16x8*>(&As[wr * 64 + mt * 16 + lr][quad * 8]);
        #pragma unroll
        for (int nt = 0; nt < 4; nt++)
            bf[nt] = *reinterpret_cast<const bf16x8*>(&Bs[wc * 64 + nt * 16 + lr][quad * 8]);
        #pragma unroll
        for (int mt = 0; mt < 4; mt++)
            #pragma unroll
            for (int nt = 0; nt < 4; nt++)
                acc[mt][nt] = __builtin_amdgcn_mfma_f32_16x16x32_bf16(af[mt], bf[nt], acc[mt][nt], 0, 0, 0);
        __syncthreads();
    }

    // epilogue
    const int colw = col0 + wc * 64;         // wave's head base col (one full head)
    const int sel = colw >> 9;               // 0=q 1=k 2=v
    const int hh = (colw & 511) >> 6;
    __hip_bfloat16* dst = sel == 0 ? qb : (sel == 1 ? kb : vb);

    float lw[4], lb[4];
    if (sel) {
        const float* w = (sel == 1) ? ln1w : ln2w;
        const float* bb = (sel == 1) ? ln1b : ln2b;
        #pragma unroll
        for (int nt = 0; nt < 4; nt++) { lw[nt] = w[nt * 16 + lr]; lb[nt] = bb[nt * 16 + lr]; }
    }

    #pragma unroll
    for (int mt = 0; mt < 4; mt++) {
        #pragma unroll
        for (int reg = 0; reg < 4; reg++) {
            int row = row0 + wr * 64 + mt * 16 + quad * 4 + reg;
            int b_ = row >> 15;
            int n = row & (NN - 1);
            float v0 = acc[mt][0][reg], v1 = acc[mt][1][reg],
                  v2 = acc[mt][2][reg], v3 = acc[mt][3][reg];
            if (sel == 0) {
                float s = inv[batch[n]];
                v0 *= s; v1 *= s; v2 *= s; v3 *= s;
            } else {
                float s = v0 + v1 + v2 + v3;
                s += __shfl_xor(s, 1); s += __shfl_xor(s, 2);
                s += __shfl_xor(s, 4); s += __shfl_xor(s, 8);
                float mu = s * (1.0f / 64.0f);
                float d0 = v0 - mu, d1 = v1 - mu, d2 = v2 - mu, d3 = v3 - mu;
                float s2 = d0 * d0 + d1 * d1 + d2 * d2 + d3 * d3;
                s2 += __shfl_xor(s2, 1); s2 += __shfl_xor(s2, 2);
                s2 += __shfl_xor(s2, 4); s2 += __shfl_xor(s2, 8);
                float rstd = rsqrtf(s2 * (1.0f / 64.0f) + 1e-6f);
                v0 = d0 * rstd * lw[0] + lb[0];
                v1 = d1 * rstd * lw[1] + lb[1];
                v2 = d2 * rstd * lw[2] + lb[2];
                v3 = d3 * rstd * lw[3] + lb[3];
            }
            size_t base = (((size_t)(b_ * HEADS + hh) << 15) + n) * 64;
            dst[base + 0 * 16 + lr] = __float2bfloat16(v0);
            dst[base + 1 * 16 + lr] = __float2bfloat16(v1);
            dst[base + 2 * 16 + lr] = __float2bfloat16(v2);
            dst[base + 3 * 16 + lr] = __float2bfloat16(v3);
        }
    }
}

// ---------------------------------------------------------------------------
// ktv[b,h,g] = sum_{n in g} k[n] (outer) v[n]  (64x64 fp32); 512 blocks.
// ---------------------------------------------------------------------------
__global__ __launch_bounds__(256) void ktv_kernel(
        const __hip_bfloat16* __restrict__ k, const __hip_bfloat16* __restrict__ v,
        const int* __restrict__ starts, const int* __restrict__ sizes,
        float* __restrict__ ktv) {
    __shared__ float ksh[4][64];
    __shared__ float vsh[4][64];
    const int bhg = blockIdx.x;
    const int g = bhg & 31;
    const int bh = bhg >> 5;
    const int s0 = starts[g];
    const int sz = sizes[g];
    const int t = threadIdx.x;
    const int dbase = (t >> 4) * 4;
    const int ebase = (t & 15) * 4;

    float acc[4][4] = {};

    for (int i = 0; i < sz; i += 4) {
        __syncthreads();
        #pragma unroll
        for (int u = 0; u < 2; u++) {
            int idx = t * 2 + u;
            int which = idx >> 8;
            int rowi = (idx >> 6) & 3;
            int d = idx & 63;
            int node = i + rowi;
            float val = 0.f;
            if (node < sz) {
                const __hip_bfloat16* src = which ? v : k;
                val = __bfloat162float(src[((size_t)bh * NN + s0 + node) * 64 + d]);
            }
            if (which) vsh[rowi][d] = val; else ksh[rowi][d] = val;
        }
        __syncthreads();
        #pragma unroll
        for (int rr = 0; rr < 4; rr++) {
            float4 kk = *reinterpret_cast<const float4*>(&ksh[rr][dbase]);
            float4 vv = *reinterpret_cast<const float4*>(&vsh[rr][ebase]);
            acc[0][0] += kk.x * vv.x; acc[0][1] += kk.x * vv.y; acc[0][2] += kk.x * vv.z; acc[0][3] += kk.x * vv.w;
            acc[1][0] += kk.y * vv.x; acc[1][1] += kk.y * vv.y; acc[1][2] += kk.y * vv.z; acc[1][3] += kk.y * vv.w;
            acc[2][0] += kk.z * vv.x; acc[2][1] += kk.z * vv.y; acc[2][2] += kk.z * vv.z; acc[2][3] += kk.z * vv.w;
            acc[3][0] += kk.w * vv.x; acc[3][1] += kk.w * vv.y; acc[3][2] += kk.w * vv.z; acc[3][3] += kk.w * vv.w;
        }
    }
    float* out = ktv + (size_t)bhg * 4096;
    #pragma unroll
    for (int di = 0; di < 4; di++)
        #pragma unroll
        for (int ei = 0; ei < 4; ei++)
            out[(dbase + di) * 64 + ebase + ei] = acc[di][ei];
}

// ---------------------------------------------------------------------------
// og[b,n,h*64+e] = sum_d q[b,h,n,d] * ktv[b,h,g(n),d,e]   (bf16 out)
// ---------------------------------------------------------------------------
__global__ __launch_bounds__(256) void apply_kernel(
        const __hip_bfloat16* __restrict__ q, const float* __restrict__ ktv,
        const int* __restrict__ starts, const int* __restrict__ sizes,
        __hip_bfloat16* __restrict__ og) {
    __shared__ float kt_sh[64][64];
    __shared__ float q_sh[8][64];
    const int bhg = blockIdx.x;
    const int chunk = blockIdx.y;
    const int g = bhg & 31;
    const int bh = bhg >> 5;
    const int b = bh >> 3;
    const int h = bh & 7;
    const int s0 = starts[g];
    const int sz = sizes[g];
    const int t = threadIdx.x;

    {
        const float4* src = reinterpret_cast<const float4*>(ktv + (size_t)bhg * 4096);
        float4* dst = reinterpret_cast<float4*>(&kt_sh[0][0]);
        #pragma unroll
        for (int i = 0; i < 4; i++) dst[t + 256 * i] = src[t + 256 * i];
    }

    const int len = (sz + 7) >> 3;
    const int n0 = chunk * len;
    const int n1 = min(n0 + len, sz);
    const int e2 = (t & 31) * 2;
    const int ns = t >> 5;

    for (int base = n0; base < n1; base += 8) {
        __syncthreads();
        #pragma unroll
        for (int u = 0; u < 2; u++) {
            int idx = t * 2 + u;
            int rr = idx >> 6;
            int d = idx & 63;
            int node = base + rr;
            q_sh[rr][d] = (node < n1)
                ? __bfloat162float(q[((size_t)bh * NN + s0 + node) * 64 + d]) : 0.f;
        }
        __syncthreads();
        float a0 = 0.f, a1 = 0.f;
        #pragma unroll 8
        for (int d = 0; d < 64; d++) {
            float qd = q_sh[ns][d];
            float2 kt = *reinterpret_cast<const float2*>(&kt_sh[d][e2]);
            a0 += qd * kt.x;
            a1 += qd * kt.y;
        }
        int node = base + ns;
        if (node < n1) {
            size_t o = ((size_t)b * NN + s0 + node) * INNER + h * 64 + e2;
            og[o]     = __float2bfloat16(a0);
            og[o + 1] = __float2bfloat16(a1);
        }
    }
}

// ---------------------------------------------------------------------------
// out = og(65536x512,bf16) @ w_out_bf16(512x512)^T + b_out -> fp32
// 128x128 tile, global_load_lds. Grid (512, 4).
// ---------------------------------------------------------------------------
__global__ __launch_bounds__(256) void out_gemm_kernel(
        const __hip_bfloat16* __restrict__ og, const __hip_bfloat16* __restrict__ wob,
        const float* __restrict__ bias, float* __restrict__ out) {
    __shared__ __hip_bfloat16 As[128][32];
    __shared__ __hip_bfloat16 Bs[128][32];
    const int row0 = blockIdx.x * 128;
    const int col0 = blockIdx.y * 128;
    const int t = threadIdx.x;
    const int lane = t & 63;
    const int wave = t >> 6;
    const int wr = wave >> 1, wc = wave & 1;
    const int quad = lane >> 4, lr = lane & 15;

    floatx4 acc[4][4] = {};

    const int srow = t >> 2;
    const int scol = (t & 3) * 8;
    const __hip_bfloat16* gA = og + (size_t)(row0 + srow) * INNER + scol;
    const __hip_bfloat16* gB = wob + (size_t)(col0 + srow) * INNER + scol;
    char* lA = (char*)&As[0][0] + t * 16;
    char* lB = (char*)&Bs[0][0] + t * 16;

    for (int k0 = 0; k0 < INNER; k0 += 32) {
        gl_lds16(gA + k0, lA);
        gl_lds16(gA + (size_t)64 * INNER + k0, lA + 4096);
        gl_lds16(gB + k0, lB);
        gl_lds16(gB + (size_t)64 * INNER + k0, lB + 4096);
        __syncthreads();
        bf16x8 af[4], bf[4];
        #pragma unroll
        for (int mt = 0; mt < 4; mt++)
            af[mt] = *reinterpret_cast<const bf16x8*>(&As[wr * 64 + mt * 16 + lr][quad * 8]);
        #pragma unroll
        for (int nt = 0; nt < 4; nt++)
            bf[nt] = *reinterpret_cast<const bf16x8*>(&Bs[wc * 64 + nt * 16 + lr][quad * 8]);
        #pragma unroll
        for (int mt = 0; mt < 4; mt++)
            #pragma unroll
            for (int nt = 0; nt < 4; nt++)
                acc[mt][nt] = __builtin_amdgcn_mfma_f32_16x16x32_bf16(af[mt], bf[nt], acc[mt][nt], 0, 0, 0);
        __syncthreads();
    }

    #pragma unroll
    for (int nt = 0; nt < 4; nt++) {
        int col = col0 + wc * 64 + nt * 16 + lr;
        float bv = bias[col];
        #pragma unroll
        for (int mt = 0; mt < 4; mt++)
            #pragma unroll
            for (int reg = 0; reg < 4; reg++) {
                int row = row0 + wr * 64 + mt * 16 + quad * 4 + reg;
                out[(size_t)row * DIM + col] = acc[mt][nt][reg] + bv;
            }
    }
}

// ---------------------------------------------------------------------------
extern "C" void kernel_launch(void* const* d_in, const int* in_sizes, int n_in,
                              void* d_out, int out_size, void* d_ws, size_t ws_size,
                              hipStream_t stream) {
    const float* x     = (const float*)d_in[0];
    const float* w_qkv = (const float*)d_in[1];
    const float* ln1w  = (const float*)d_in[2];
    const float* ln1b  = (const float*)d_in[3];
    const float* ln2w  = (const float*)d_in[4];
    const float* ln2b  = (const float*)d_in[5];
    const float* w_out = (const float*)d_in[6];
    const float* b_out = (const float*)d_in[7];
    const int*   batch = (const int*)d_in[8];
    float* out = (float*)d_out;

    char* ws = (char*)d_ws;
    const size_t MB = 1u << 20;
    __hip_bfloat16* qb  = (__hip_bfloat16*)(ws);              // 64 MiB
    __hip_bfloat16* kb  = (__hip_bfloat16*)(ws + 64 * MB);    // 64 MiB
    __hip_bfloat16* vb  = (__hip_bfloat16*)(ws + 128 * MB);   // 64 MiB
    // region [192,256): xb during convert+qkv_gemm, then og (xb dead after qkv)
    __hip_bfloat16* xb  = (__hip_bfloat16*)(ws + 192 * MB);
    __hip_bfloat16* og  = (__hip_bfloat16*)(ws + 192 * MB);
    // region [256,264): wb during convert+qkv_gemm, then ktv (wb dead after qkv)
    __hip_bfloat16* wb  = (__hip_bfloat16*)(ws + 256 * MB);   // 1.5 MiB
    float*          ktv = (float*)(ws + 256 * MB);            // 8 MiB
    __hip_bfloat16* wob = (__hip_bfloat16*)(ws + 264 * MB);   // 0.5 MiB
    int*   starts = (int*)(ws + 264 * MB + 512 * 1024);
    int*   sizes  = (int*)(ws + 264 * MB + 512 * 1024 + 4096);
    float* inv    = (float*)(ws + 264 * MB + 512 * 1024 + 8192);

    graph_info_kernel<<<1, 64, 0, stream>>>(batch, starts, sizes, inv);
    convert_kernel<<<(M_ROWS * DIM / 8 + 255) / 256, 256, 0, stream>>>(x, xb, M_ROWS * DIM / 8);
    convert_kernel<<<(3 * INNER * DIM / 8 + 255) / 256, 256, 0, stream>>>(w_qkv, wb, 3 * INNER * DIM / 8);
    convert_kernel<<<(DIM * INNER / 8 + 255) / 256, 256, 0, stream>>>(w_out, wob, DIM * INNER / 8);
    qkv_gemm_kernel<<<dim3(M_ROWS / 128, (3 * INNER) / 128), 256, 0, stream>>>(
        xb, wb, ln1w, ln1b, ln2w, ln2b, inv, batch, qb, kb, vb);
    ktv_kernel<<<BATCH * HEADS * G, 256, 0, stream>>>(kb, vb, starts, sizes, ktv);
    apply_kernel<<<dim3(BATCH * HEADS * G, 8), 256, 0, stream>>>(
        qb, ktv, starts, sizes, og);
    out_gemm_kernel<<<dim3(M_ROWS / 128, DIM / 128), 256, 0, stream>>>(
        og, wob, b_out, out);
}

// Round 3
// 634.771 us; speedup vs baseline: 2.0514x; 1.3694x over previous
//
#include <hip/hip_runtime.h>
#include <hip/hip_bf16.h>
#include <stdint.h>

#define BATCH 2
#define NN 32768
#define DIM 512
#define HEADS 8
#define INNER 512
#define G 32
#define M_ROWS (BATCH * NN)   // 65536
#define MAXCHUNK 576

typedef __attribute__((ext_vector_type(8))) short bf16x8;
typedef __attribute__((ext_vector_type(4))) float floatx4;

__device__ __forceinline__ void gl_lds16(const void* g, void* l) {
    __builtin_amdgcn_global_load_lds(
        (const __attribute__((address_space(1))) uint32_t*)g,
        (__attribute__((address_space(3))) uint32_t*)l, 16, 0, 0);
}

__device__ __forceinline__ short f2bs(float f) {
    __hip_bfloat16 h = __float2bfloat16(f);
    return *reinterpret_cast<short*>(&h);
}

// ---------------------------------------------------------------------------
// graph info + chunk table (sorted batch -> binary search; serial chunk build)
// ---------------------------------------------------------------------------
__global__ void graph_info_kernel(const int* __restrict__ batch,
                                  int* __restrict__ starts,
                                  int* __restrict__ sizes,
                                  float* __restrict__ inv,
                                  int* __restrict__ crow0,
                                  int* __restrict__ crows,
                                  int* __restrict__ cbg,
                                  int* __restrict__ cnt) {
    __shared__ int bound[G + 1];
    int g = threadIdx.x;
    if (g <= G) {
        int lo = 0, hi = NN;
        while (lo < hi) { int mid = (lo + hi) >> 1; if (batch[mid] < g) lo = mid + 1; else hi = mid; }
        bound[g] = lo;
    }
    __syncthreads();
    if (g < G) {
        int s0 = bound[g], s1 = bound[g + 1];
        starts[g] = s0;
        int c = s1 - s0;
        sizes[g] = c;
        inv[g] = c ? 1.0f / (float)c : 0.0f;
    }
    if (g == 0) {
        int c = 0;
        for (int b = 0; b < BATCH; b++)
            for (int gg = 0; gg < G; gg++) {
                int s = bound[gg], sz = bound[gg + 1] - s;
                for (int i = 0; i < sz; i += 128) {
                    crow0[c] = b * NN + s + i;
                    crows[c] = min(128, sz - i);
                    cbg[c]   = b * G + gg;
                    c++;
                }
            }
        *cnt = c;
    }
}

// ---------------------------------------------------------------------------
// fp32 -> bf16 convert, 8 elements/thread
// ---------------------------------------------------------------------------
__global__ __launch_bounds__(256) void convert_kernel(
        const float* __restrict__ in, __hip_bfloat16* __restrict__ out, int n8) {
    int i = blockIdx.x * 256 + threadIdx.x;
    if (i >= n8) return;
    const float4* p = reinterpret_cast<const float4*>(in) + (size_t)i * 2;
    float4 a = p[0], b = p[1];
    __hip_bfloat16 o[8];
    o[0] = __float2bfloat16(a.x); o[1] = __float2bfloat16(a.y);
    o[2] = __float2bfloat16(a.z); o[3] = __float2bfloat16(a.w);
    o[4] = __float2bfloat16(b.x); o[5] = __float2bfloat16(b.y);
    o[6] = __float2bfloat16(b.z); o[7] = __float2bfloat16(b.w);
    *reinterpret_cast<float4*>(out + (size_t)i * 8) = *reinterpret_cast<float4*>(o);
}

// ---------------------------------------------------------------------------
// QKV GEMM, 128x128 tile, global_load_lds, bf16 MFMA, fused LN/q-scale.
// Grid (12 col-tiles FAST, 512 row-tiles slow): consecutive blocks share the
// A row-panel -> A fetched ~once from HBM; B (1.5 MB) is L2-resident.
// q written in [B][N][h*64+d] row-major (final-GEMM A layout); k,v in [b,h,n,d].
// ---------------------------------------------------------------------------
__global__ __launch_bounds__(256) void qkv_gemm_kernel(
        const __hip_bfloat16* __restrict__ xb, const __hip_bfloat16* __restrict__ wb,
        const float* __restrict__ ln1w, const float* __restrict__ ln1b,
        const float* __restrict__ ln2w, const float* __restrict__ ln2b,
        const float* __restrict__ inv, const int* __restrict__ batch,
        __hip_bfloat16* __restrict__ qn, __hip_bfloat16* __restrict__ kb,
        __hip_bfloat16* __restrict__ vb) {
    __shared__ __hip_bfloat16 As[128][32];
    __shared__ __hip_bfloat16 Bs[128][32];
    const int row0 = blockIdx.y * 128;
    const int col0 = blockIdx.x * 128;
    const int t = threadIdx.x;
    const int lane = t & 63;
    const int wave = t >> 6;
    const int wr = wave >> 1, wc = wave & 1;
    const int quad = lane >> 4, lr = lane & 15;

    floatx4 acc[4][4] = {};

    const int srow = t >> 2;
    const int scol = (t & 3) * 8;
    const __hip_bfloat16* gA = xb + (size_t)(row0 + srow) * DIM + scol;
    const __hip_bfloat16* gB = wb + (size_t)(col0 + srow) * DIM + scol;
    char* lA = (char*)&As[0][0] + t * 16;
    char* lB = (char*)&Bs[0][0] + t * 16;

    for (int k0 = 0; k0 < DIM; k0 += 32) {
        gl_lds16(gA + k0, lA);
        gl_lds16(gA + (size_t)64 * DIM + k0, lA + 4096);
        gl_lds16(gB + k0, lB);
        gl_lds16(gB + (size_t)64 * DIM + k0, lB + 4096);
        __syncthreads();
        bf16x8 af[4], bf[4];
        #pragma unroll
        for (int mt = 0; mt < 4; mt++)
            af[mt] = *reinterpret_cast<const bf16x8*>(&As[wr * 64 + mt * 16 + lr][quad * 8]);
        #pragma unroll
        for (int nt = 0; nt < 4; nt++)
            bf[nt] = *reinterpret_cast<const bf16x8*>(&Bs[wc * 64 + nt * 16 + lr][quad * 8]);
        #pragma unroll
        for (int mt = 0; mt < 4; mt++)
            #pragma unroll
            for (int nt = 0; nt < 4; nt++)
                acc[mt][nt] = __builtin_amdgcn_mfma_f32_16x16x32_bf16(af[mt], bf[nt], acc[mt][nt], 0, 0, 0);
        __syncthreads();
    }

    const int colw = col0 + wc * 64;
    const int sel = colw >> 9;               // 0=q 1=k 2=v
    const int hh = (colw & 511) >> 6;

    float lw[4], lb[4];
    if (sel) {
        const float* w = (sel == 1) ? ln1w : ln2w;
        const float* bb = (sel == 1) ? ln1b : ln2b;
        #pragma unroll
        for (int nt = 0; nt < 4; nt++) { lw[nt] = w[nt * 16 + lr]; lb[nt] = bb[nt * 16 + lr]; }
    }
    __hip_bfloat16* dstkv = (sel == 1) ? kb : vb;

    #pragma unroll
    for (int mt = 0; mt < 4; mt++) {
        #pragma unroll
        for (int reg = 0; reg < 4; reg++) {
            int row = row0 + wr * 64 + mt * 16 + quad * 4 + reg;
            int b_ = row >> 15;
            int n = row & (NN - 1);
            float v0 = acc[mt][0][reg], v1 = acc[mt][1][reg],
                  v2 = acc[mt][2][reg], v3 = acc[mt][3][reg];
            size_t base;
            __hip_bfloat16* dst;
            if (sel == 0) {
                float s = inv[batch[n]];
                v0 *= s; v1 *= s; v2 *= s; v3 *= s;
                base = ((size_t)b_ * NN + n) * INNER + hh * 64;
                dst = qn;
            } else {
                float s = v0 + v1 + v2 + v3;
                s += __shfl_xor(s, 1); s += __shfl_xor(s, 2);
                s += __shfl_xor(s, 4); s += __shfl_xor(s, 8);
                float mu = s * (1.0f / 64.0f);
                float d0 = v0 - mu, d1 = v1 - mu, d2 = v2 - mu, d3 = v3 - mu;
                float s2 = d0 * d0 + d1 * d1 + d2 * d2 + d3 * d3;
                s2 += __shfl_xor(s2, 1); s2 += __shfl_xor(s2, 2);
                s2 += __shfl_xor(s2, 4); s2 += __shfl_xor(s2, 8);
                float rstd = rsqrtf(s2 * (1.0f / 64.0f) + 1e-6f);
                v0 = d0 * rstd * lw[0] + lb[0];
                v1 = d1 * rstd * lw[1] + lb[1];
                v2 = d2 * rstd * lw[2] + lb[2];
                v3 = d3 * rstd * lw[3] + lb[3];
                base = (((size_t)(b_ * HEADS + hh) << 15) + n) * 64;
                dst = dstkv;
            }
            dst[base + 0 * 16 + lr] = __float2bfloat16(v0);
            dst[base + 1 * 16 + lr] = __float2bfloat16(v1);
            dst[base + 2 * 16 + lr] = __float2bfloat16(v2);
            dst[base + 3 * 16 + lr] = __float2bfloat16(v3);
        }
    }
}

// ---------------------------------------------------------------------------
// Fused ktv + W2: per (b,h,g) block:
//   ktv[d,e] = sum_n k[n,d] v[n,e]      (MFMA, K=node chunks of 32)
//   W2T[bg][c][h*64+d] = sum_e w_out[c,h*64+e] * ktv[d,e]   (MFMA, bf16 out)
// ---------------------------------------------------------------------------
__global__ __launch_bounds__(256) void ktv_w2_kernel(
        const short* __restrict__ kb, const short* __restrict__ vb,
        const short* __restrict__ wob,
        const int* __restrict__ starts, const int* __restrict__ sizes,
        short* __restrict__ w2t) {
    __shared__ short k_sh[32][64];
    __shared__ short v_sh[32][64];
    __shared__ short kt_sh[64][72];    // pad 72: 144B rows (16B-aligned, conflict-light)
    const int bhg = blockIdx.x;
    const int g = bhg & 31;
    const int bh = bhg >> 5;
    const int b = bh >> 3;
    const int h = bh & 7;
    const int s0 = starts[g];
    const int sz = sizes[g];
    const int t = threadIdx.x;
    const int lane = t & 63;
    const int w = t >> 6;
    const int quad = lane >> 4, lr = lane & 15;

    floatx4 acc[4] = {};
    const int node = t >> 3;
    const int cs = (t & 7) * 8;
    const size_t gbase = ((size_t)bh * NN + s0) * 64;

    for (int c0 = 0; c0 < sz; c0 += 32) {
        __syncthreads();
        float4 kz = {0.f, 0.f, 0.f, 0.f}, vz = {0.f, 0.f, 0.f, 0.f};
        if (c0 + node < sz) {
            kz = *reinterpret_cast<const float4*>(kb + gbase + (size_t)(c0 + node) * 64 + cs);
            vz = *reinterpret_cast<const float4*>(vb + gbase + (size_t)(c0 + node) * 64 + cs);
        }
        *reinterpret_cast<float4*>(&k_sh[node][cs]) = kz;
        *reinterpret_cast<float4*>(&v_sh[node][cs]) = vz;
        __syncthreads();
        bf16x8 af;
        #pragma unroll
        for (int j = 0; j < 8; j++) af[j] = k_sh[quad * 8 + j][w * 16 + lr];
        #pragma unroll
        for (int et = 0; et < 4; et++) {
            bf16x8 bfr;
            #pragma unroll
            for (int j = 0; j < 8; j++) bfr[j] = v_sh[quad * 8 + j][et * 16 + lr];
            acc[et] = __builtin_amdgcn_mfma_f32_16x16x32_bf16(af, bfr, acc[et], 0, 0, 0);
        }
    }
    __syncthreads();
    #pragma unroll
    for (int et = 0; et < 4; et++)
        #pragma unroll
        for (int reg = 0; reg < 4; reg++)
            kt_sh[w * 16 + quad * 4 + reg][et * 16 + lr] = f2bs(acc[et][reg]);
    __syncthreads();

    // phase 3: W2T rows [w*128, w*128+128) of this bg, cols h*64..h*64+63
    const short* wsl = wob + h * 64;
    short* w2 = w2t + (size_t)(b * G + g) * 512 * 512 + h * 64;
    bf16x8 b0[4], b1[4];
    #pragma unroll
    for (int dt = 0; dt < 4; dt++) {
        b0[dt] = *reinterpret_cast<const bf16x8*>(&kt_sh[dt * 16 + lr][quad * 8]);
        b1[dt] = *reinterpret_cast<const bf16x8*>(&kt_sh[dt * 16 + lr][quad * 8 + 32]);
    }
    for (int ct = 0; ct < 8; ct++) {
        int c = w * 128 + ct * 16 + lr;
        bf16x8 a0 = *reinterpret_cast<const bf16x8*>(wsl + (size_t)c * INNER + quad * 8);
        bf16x8 a1 = *reinterpret_cast<const bf16x8*>(wsl + (size_t)c * INNER + 32 + quad * 8);
        #pragma unroll
        for (int dt = 0; dt < 4; dt++) {
            floatx4 d = {0.f, 0.f, 0.f, 0.f};
            d = __builtin_amdgcn_mfma_f32_16x16x32_bf16(a0, b0[dt], d, 0, 0, 0);
            d = __builtin_amdgcn_mfma_f32_16x16x32_bf16(a1, b1[dt], d, 0, 0, 0);
            #pragma unroll
            for (int reg = 0; reg < 4; reg++) {
                int crow = w * 128 + ct * 16 + quad * 4 + reg;
                w2[(size_t)crow * 512 + dt * 16 + lr] = f2bs(d[reg]);
            }
        }
    }
}

// ---------------------------------------------------------------------------
// Final segmented GEMM: out[row,:] = qn[row,:] @ W2T[bg]^T + b_out  (fp32 out)
// Grid (4 col-tiles FAST, 576 chunks). Full-tile gl_lds staging; masked stores.
// ---------------------------------------------------------------------------
__global__ __launch_bounds__(256) void final_gemm_kernel(
        const __hip_bfloat16* __restrict__ qn, const __hip_bfloat16* __restrict__ w2t,
        const float* __restrict__ bias,
        const int* __restrict__ crow0, const int* __restrict__ crows,
        const int* __restrict__ cbg, const int* __restrict__ cnt,
        float* __restrict__ out) {
    const int chunk = blockIdx.y;
    if (chunk >= *cnt) return;
    __shared__ __hip_bfloat16 As[128][32];
    __shared__ __hip_bfloat16 Bs[128][32];
    const int row0  = crow0[chunk];
    const int nrows = crows[chunk];
    const int bg    = cbg[chunk];
    const int col0 = blockIdx.x * 128;
    const int t = threadIdx.x;
    const int lane = t & 63;
    const int wave = t >> 6;
    const int wr = wave >> 1, wc = wave & 1;
    const int quad = lane >> 4, lr = lane & 15;

    floatx4 acc[4][4] = {};

    const int srow = t >> 2;
    const int scol = (t & 3) * 8;
    const __hip_bfloat16* gA = qn + (size_t)(row0 + srow) * INNER + scol;
    const __hip_bfloat16* gB = w2t + (size_t)bg * 512 * 512 + (size_t)(col0 + srow) * 512 + scol;
    char* lA = (char*)&As[0][0] + t * 16;
    char* lB = (char*)&Bs[0][0] + t * 16;

    for (int k0 = 0; k0 < INNER; k0 += 32) {
        gl_lds16(gA + k0, lA);
        gl_lds16(gA + (size_t)64 * INNER + k0, lA + 4096);
        gl_lds16(gB + k0, lB);
        gl_lds16(gB + (size_t)64 * 512 + k0, lB + 4096);
        __syncthreads();
        bf16x8 af[4], bf[4];
        #pragma unroll
        for (int mt = 0; mt < 4; mt++)
            af[mt] = *reinterpret_cast<const bf16x8*>(&As[wr * 64 + mt * 16 + lr][quad * 8]);
        #pragma unroll
        for (int nt = 0; nt < 4; nt++)
            bf[nt] = *reinterpret_cast<const bf16x8*>(&Bs[wc * 64 + nt * 16 + lr][quad * 8]);
        #pragma unroll
        for (int mt = 0; mt < 4; mt++)
            #pragma unroll
            for (int nt = 0; nt < 4; nt++)
                acc[mt][nt] = __builtin_amdgcn_mfma_f32_16x16x32_bf16(af[mt], bf[nt], acc[mt][nt], 0, 0, 0);
        __syncthreads();
    }

    #pragma unroll
    for (int nt = 0; nt < 4; nt++) {
        int col = col0 + wc * 64 + nt * 16 + lr;
        float bv = bias[col];
        #pragma unroll
        for (int mt = 0; mt < 4; mt++)
            #pragma unroll
            for (int reg = 0; reg < 4; reg++) {
                int rl = wr * 64 + mt * 16 + quad * 4 + reg;
                if (rl < nrows)
                    out[(size_t)(row0 + rl) * DIM + col] = acc[mt][nt][reg] + bv;
            }
    }
}

// ---------------------------------------------------------------------------
extern "C" void kernel_launch(void* const* d_in, const int* in_sizes, int n_in,
                              void* d_out, int out_size, void* d_ws, size_t ws_size,
                              hipStream_t stream) {
    const float* x     = (const float*)d_in[0];
    const float* w_qkv = (const float*)d_in[1];
    const float* ln1w  = (const float*)d_in[2];
    const float* ln1b  = (const float*)d_in[3];
    const float* ln2w  = (const float*)d_in[4];
    const float* ln2b  = (const float*)d_in[5];
    const float* w_out = (const float*)d_in[6];
    const float* b_out = (const float*)d_in[7];
    const int*   batch = (const int*)d_in[8];
    float* out = (float*)d_out;

    char* ws = (char*)d_ws;
    const size_t MB = 1u << 20;
    __hip_bfloat16* qn  = (__hip_bfloat16*)(ws);              // 64 MiB
    __hip_bfloat16* kb  = (__hip_bfloat16*)(ws + 64 * MB);    // 64 MiB
    __hip_bfloat16* vb  = (__hip_bfloat16*)(ws + 128 * MB);   // 64 MiB
    // region [192,256): xb during convert+qkv, then W2T (32 MiB) afterwards
    __hip_bfloat16* xb  = (__hip_bfloat16*)(ws + 192 * MB);
    __hip_bfloat16* w2t = (__hip_bfloat16*)(ws + 192 * MB);
    __hip_bfloat16* wb  = (__hip_bfloat16*)(ws + 256 * MB);   // 1.5 MiB
    __hip_bfloat16* wob = (__hip_bfloat16*)(ws + 258 * MB);   // 0.5 MiB
    char* meta = ws + 259 * MB;
    int*   starts = (int*)(meta);
    int*   sizes  = (int*)(meta + 128);
    float* inv    = (float*)(meta + 256);
    int*   crow0  = (int*)(meta + 512);
    int*   crows  = (int*)(meta + 512 + 4096);
    int*   cbg    = (int*)(meta + 512 + 8192);
    int*   cnt    = (int*)(meta + 512 + 12288);

    graph_info_kernel<<<1, 64, 0, stream>>>(batch, starts, sizes, inv,
                                            crow0, crows, cbg, cnt);
    convert_kernel<<<(M_ROWS * DIM / 8 + 255) / 256, 256, 0, stream>>>(x, xb, M_ROWS * DIM / 8);
    convert_kernel<<<(3 * INNER * DIM / 8 + 255) / 256, 256, 0, stream>>>(w_qkv, wb, 3 * INNER * DIM / 8);
    convert_kernel<<<(DIM * INNER / 8 + 255) / 256, 256, 0, stream>>>(w_out, wob, DIM * INNER / 8);
    qkv_gemm_kernel<<<dim3((3 * INNER) / 128, M_ROWS / 128), 256, 0, stream>>>(
        xb, wb, ln1w, ln1b, ln2w, ln2b, inv, batch, qn, kb, vb);
    ktv_w2_kernel<<<BATCH * HEADS * G, 256, 0, stream>>>(
        (const short*)kb, (const short*)vb, (const short*)wob, starts, sizes, (short*)w2t);
    final_gemm_kernel<<<dim3(4, MAXCHUNK), 256, 0, stream>>>(
        qn, w2t, b_out, crow0, crows, cbg, cnt, out);
}